// Round 7
// baseline (277.201 us; speedup 1.0000x reference)
//
#include <hip/hip_runtime.h>
#include <stdint.h>

typedef unsigned int u32;
typedef unsigned long long u64;

constexpr int L   = 4;
constexpr int S   = 4;
constexpr int NM  = 16;
constexpr int HID = 32;
constexpr int BLK = 256;                       // block size for prep kernels
constexpr int BLK4 = 1024;                     // k4 block: 16 waves, weights amortized
constexpr int NFRAG = 7;                       // A-frags per (l,s): L1:1, L2:2, L3:2, L4:2
constexpr int WF_ENTRIES = L * S * NFRAG * 64; // 7168 uint4 entries
constexpr int WS_PERM_INT = (256 + WF_ENTRIES * 16) / 4;  // perm after hdr+wfrag

typedef short  s16x8  __attribute__((ext_vector_type(8)));
typedef float  f32x16 __attribute__((ext_vector_type(16)));
typedef float  f32x4  __attribute__((ext_vector_type(4)));
typedef unsigned int u32x2 __attribute__((ext_vector_type(2)));

// ws: [0,64B) hdr ints: [0..3] counts (k1), [4..7] scatter cursors (k3).
// wfrag uint4 at byte 256. perm at int WS_PERM_INT (N + 4*BLK4 ints).

__device__ __forceinline__ int load_species(const int* sp, int i64, int n) {
    return i64 ? sp[2 * n] : sp[n];
}

// Pre-swizzle weights into 32x32x16 A-fragment order (transposed: A[m=out][k=in]).
// Entry e = ((l*S+s)*NFRAG + f)*64 + lane. Lane holds k = 8*(lane>>5)+j, m = lane&31.
// Block 0 also zeroes hdr[0..8] (stream-ordered before k1_hist/k3_scatter).
__global__ void k_wprep(const void* __restrict__ W1, const void* __restrict__ W2,
                        const void* __restrict__ W3, const void* __restrict__ W4,
                        const u32* __restrict__ rfw, int* __restrict__ hdr,
                        uint4* __restrict__ wf) {
    __shared__ int sf32;
    int tid = threadIdx.x;
    if (tid < 64) {
        u32 w  = rfw[tid];
        u32 lo = w & 0xffffu;
        u32 ex = (lo >> 7) & 0xffu;
        int plausible = (lo == 0u || (ex >= 90u && ex <= 141u)) ? 1 : 0;
        u64 pm = __ballot(plausible);
        if (tid == 0) sf32 = (__popcll(pm) < 48) ? 1 : 0;   // fp32 inputs
    }
    if (blockIdx.x == 0 && tid < 9) hdr[tid] = 0;
    __syncthreads();
    int isf32 = sf32;

    int e = blockIdx.x * BLK + tid;
    if (e >= WF_ENTRIES) return;
    int lam = e & 63;
    int f   = (e >> 6) % NFRAG;
    int ls  = e / (64 * NFRAG);
    int m = lam & 31, h = lam >> 5;
    unsigned short vals[8];
#pragma unroll
    for (int j = 0; j < 8; j++) {
        int k = 8 * h + j;
        const void* base; size_t off; bool zero = false;
        if (f == 0)      { base = W1; off = (size_t)ls * 512  + (size_t)k * 32 + m; }
        else if (f <= 2) { base = W2; off = (size_t)ls * 1024 + (size_t)(k + 16 * (f - 1)) * 32 + m; }
        else if (f <= 4) { base = W3; off = (size_t)ls * 1024 + (size_t)(k + 16 * (f - 3)) * 32 + m; }
        else             { zero = (m >= NM); base = W4;
                           off = (size_t)ls * 512 + (size_t)(k + 16 * (f - 5)) * NM + (m & 15); }
        unsigned short v;
        if (zero) v = 0;
        else if (isf32) {
            u32 u = __float_as_uint(((const float*)base)[off]);
            u32 r = ((u >> 16) & 1u) + 0x7fffu;
            v = (unsigned short)((u + r) >> 16);
        } else v = ((const unsigned short*)base)[off];
        vals[j] = v;
    }
    uint4 q;
    q.x = vals[0] | ((u32)vals[1] << 16);
    q.y = vals[2] | ((u32)vals[3] << 16);
    q.z = vals[4] | ((u32)vals[5] << 16);
    q.w = vals[6] | ((u32)vals[7] << 16);
    wf[e] = q;
}

// 4 elems/thread histogram: 489 blocks, 4 global atomics/block.
__global__ void k1_hist(const int* __restrict__ sp, int* __restrict__ hdr, int N) {
    __shared__ int cnt[S];
    __shared__ int si64;
    int t = threadIdx.x;
    if (t < 64) {
        u64 om = __ballot(((const u32*)sp)[2 * t + 1] != 0u);
        if (t == 0) si64 = (om == 0ull) ? 1 : 0;
    }
    if (t < S) cnt[t] = 0;
    __syncthreads();
    int i64 = si64;
    int base = blockIdx.x * (BLK * 4) + t * 4;
    if (base + 3 < N) {
        int s0, s1, s2, s3;
        if (i64) {
            int4 a = ((const int4*)sp)[base / 2];
            int4 b = ((const int4*)sp)[base / 2 + 1];
            s0 = a.x; s1 = a.z; s2 = b.x; s3 = b.z;
        } else {
            int4 a = ((const int4*)sp)[base / 4];
            s0 = a.x; s1 = a.y; s2 = a.z; s3 = a.w;
        }
        atomicAdd(&cnt[s0], 1); atomicAdd(&cnt[s1], 1);
        atomicAdd(&cnt[s2], 1); atomicAdd(&cnt[s3], 1);
    } else {
        for (int k = 0; k < 4; k++) {
            int n = base + k;
            if (n < N) atomicAdd(&cnt[load_species(sp, i64, n)], 1);
        }
    }
    __syncthreads();
    if (t < S) atomicAdd(&hdr[t], cnt[t]);
}

// 4 elems/thread scatter: block-local ranks, one cursor bump/species/block.
// Species regions padded to BLK4 (k4's block size).
__global__ void k3_scatter(const int* __restrict__ sp, int* __restrict__ hdr,
                           int* __restrict__ perm, int N) {
    __shared__ int cnt[S];
    __shared__ int base[S];
    __shared__ int bp[S + 1];
    __shared__ int cs[S];
    __shared__ int si64;
    int t = threadIdx.x;
    if (t < 64) {
        u64 om = __ballot(((const u32*)sp)[2 * t + 1] != 0u);
        if (t == 0) si64 = (om == 0ull) ? 1 : 0;
    }
    if (t == 0) {
        int acc = 0;
        for (int q = 0; q < S; q++) {
            cs[q] = hdr[q];
            bp[q] = acc;
            acc += (cs[q] + BLK4 - 1) & ~(BLK4 - 1);
        }
        bp[S] = acc;
    }
    if (t < S) cnt[t] = 0;
    __syncthreads();
    int i64 = si64;
    int nb0 = blockIdx.x * (BLK * 4) + t * 4;
    int s_[4], r_[4];
    bool v_[4];
    if (nb0 + 3 < N) {
        if (i64) {
            int4 a = ((const int4*)sp)[nb0 / 2];
            int4 b = ((const int4*)sp)[nb0 / 2 + 1];
            s_[0] = a.x; s_[1] = a.z; s_[2] = b.x; s_[3] = b.z;
        } else {
            int4 a = ((const int4*)sp)[nb0 / 4];
            s_[0] = a.x; s_[1] = a.y; s_[2] = a.z; s_[3] = a.w;
        }
        v_[0] = v_[1] = v_[2] = v_[3] = true;
    } else {
        for (int k = 0; k < 4; k++) {
            int n = nb0 + k;
            v_[k] = (n < N);
            s_[k] = v_[k] ? load_species(sp, i64, n) : 0;
        }
    }
#pragma unroll
    for (int k = 0; k < 4; k++)
        if (v_[k]) r_[k] = atomicAdd(&cnt[s_[k]], 1);
    __syncthreads();
    if (t < S) base[t] = bp[t] + atomicAdd(&hdr[4 + t], cnt[t]);
    __syncthreads();
#pragma unroll
    for (int k = 0; k < 4; k++)
        if (v_[k]) perm[base[s_[k]] + r_[k]] = nb0 + k;
    if (blockIdx.x == 0) {
        for (int q = 0; q < S; q++)
            for (int i = bp[q] + cs[q] + t; i < bp[q + 1]; i += BLK) perm[i] = -1;
    }
}

// packed fp32->bf16 (RNE) — single instruction; tolerance 0.125 >> RNE/half-up delta
__device__ __forceinline__ u32 cvt_pk_bf16(float a, float b) {
    u32 r;
    asm("v_cvt_pk_bf16_f32 %0, %1, %2" : "=v"(r) : "v"(a), "v"(b));
    return r;
}

__device__ __forceinline__ float silu(float v) {
    float e = __expf(-v);
    return v * __builtin_amdgcn_rcpf(1.0f + e);
}

// D (C/D layout) -> next-layer B frags (Ba: k=0..15, Bb: k=16..31), with SiLU.
// Cross-half exchange via v_permlane32_swap; packs via v_cvt_pk_bf16_f32.
__device__ __forceinline__ void d_to_b(const f32x16& d, s16x8& Ba, s16x8& Bb) {
    u32 P[8];
#pragma unroll
    for (int i = 0; i < 8; i++)
        P[i] = cvt_pk_bf16(silu(d[2 * i]), silu(d[2 * i + 1]));
    u32x2 r02 = __builtin_amdgcn_permlane32_swap(P[0], P[2], false, false);
    u32x2 r13 = __builtin_amdgcn_permlane32_swap(P[1], P[3], false, false);
    u32x2 r46 = __builtin_amdgcn_permlane32_swap(P[4], P[6], false, false);
    u32x2 r57 = __builtin_amdgcn_permlane32_swap(P[5], P[7], false, false);
    Ba = __builtin_bit_cast(s16x8, make_uint4(r02[0], r13[0], r02[1], r13[1]));
    Bb = __builtin_bit_cast(s16x8, make_uint4(r46[0], r57[0], r46[1], r57[1]));
}

__device__ __forceinline__ s16x8 bf16pack4(uint4 q0, uint4 q1) {
    u32 w0 = cvt_pk_bf16(__uint_as_float(q0.x), __uint_as_float(q0.y));
    u32 w1 = cvt_pk_bf16(__uint_as_float(q0.z), __uint_as_float(q0.w));
    u32 w2 = cvt_pk_bf16(__uint_as_float(q1.x), __uint_as_float(q1.y));
    u32 w3 = cvt_pk_bf16(__uint_as_float(q1.z), __uint_as_float(q1.w));
    return __builtin_bit_cast(s16x8, make_uint4(w0, w1, w2, w3));
}

// Per-wave half-row scratch stride: 32 data words + 4 pad. 16 pairs per batch.
constexpr int SCW = 36;
constexpr int NWV = BLK4 / 64;               // 16 waves per k4 block

__global__ __launch_bounds__(BLK4, 2) void k4_mlp(
    const void* __restrict__ rf, const int* __restrict__ hdr,
    const int* __restrict__ perm, const uint4* __restrict__ wf,
    void* __restrict__ outp)
{
    __shared__ uint4 lw[L * NFRAG * 64];     // 28672 B: all weight frags (16-wave amortized)
    __shared__ float sc[NWV][16 * SCW];      // 36864 B: per-wave 16-pair scratch
    __shared__ int   sn[NWV][2][32];         // 4096 B: per-wave pair indices
    __shared__ int   sf32;

    int tid = threadIdx.x;

    // bases from counts (padded prefix, BLK4-aligned to match k3)
    int c0 = hdr[0], c1 = hdr[1], c2 = hdr[2], c3 = hdr[3];
    int b1 = (c0 + BLK4 - 1) & ~(BLK4 - 1);
    int b2 = b1 + ((c1 + BLK4 - 1) & ~(BLK4 - 1));
    int b3 = b2 + ((c2 + BLK4 - 1) & ~(BLK4 - 1));
    int b4 = b3 + ((c3 + BLK4 - 1) & ~(BLK4 - 1));
    int p0 = blockIdx.x * BLK4;
    if (p0 >= b4) return;                    // uniform: whole block exits
    int s = (p0 >= b3) ? 3 : ((p0 >= b2) ? 2 : ((p0 >= b1) ? 1 : 0));
    s = __builtin_amdgcn_readfirstlane(s);

    if (tid < 64) {                          // inline fp32 detect (256B broadcast)
        u32 w  = ((const u32*)rf)[tid];
        u32 lo = w & 0xffffu;
        u32 ex = (lo >> 7) & 0xffu;
        int plausible = (lo == 0u || (ex >= 90u && ex <= 141u)) ? 1 : 0;
        u64 pm = __ballot(plausible);
        if (tid == 0) sf32 = (__popcll(pm) < 48) ? 1 : 0;
    }

    // stage all weight frags to LDS (1792 entries, 1024 threads -> 2 chunks)
#pragma unroll
    for (int c = 0; c < 2; c++) {
        int idx = tid + c * BLK4;
        if (idx < L * NFRAG * 64) {
            int l = idx / (NFRAG * 64);
            int r = idx - l * (NFRAG * 64);
            lw[idx] = wf[(size_t)((l * S + s) * NFRAG) * 64 + r];
        }
    }

    int wv   = tid >> 6;
    int lane = tid & 63;
    int col  = lane & 31;
    int h    = lane >> 5;

    int n_t[2];
#pragma unroll
    for (int t = 0; t < 2; t++) {
        n_t[t] = perm[p0 + wv * 64 + t * 32 + col];
        sn[wv][t][col] = n_t[t];
    }
    __syncthreads();
    int isf32 = sf32;

    if (isf32) {
        // ---- fp32: j=(lp,t) loop, TWO independent l-chains interleaved (2x ILP),
        //      128B half-row stores via 16-pair LDS transpose batches ----
        const char* xb = (const char*)rf;
        int nn0 = n_t[0] < 0 ? 0 : n_t[0];
        int nn1 = n_t[1] < 0 ? 0 : n_t[1];
        const uint4* rp0 = (const uint4*)(xb + (size_t)nn0 * 256 + h * 32);
        const uint4* rp1 = (const uint4*)(xb + (size_t)nn1 * 256 + h * 32);

        int rg = lane >> 3;                  // 0..7: half-row group for stores
        int cc = lane & 7;                   // 0..7: 16B chunk within a 128B half-row
        int bh = col >> 4;                   // which 16-pair batch this lane's data is in
        int pr = col & 15;                   // pair index within batch
        float* scb = &sc[wv][0];

        // double-buffered input rows: rawb[buf][li*2 + half]
        uint4 rawb[2][4];
        rawb[0][0] = rp0[0]; rawb[0][1] = rp0[1];   // j=0: l=0
        rawb[0][2] = rp0[4]; rawb[0][3] = rp0[5];   //      l=1

#pragma unroll
        for (int j = 0; j < 4; j++) {               // j = lp*2 + t
            int lp = j >> 1, t = j & 1;
            if (j < 3) {                            // prefetch next (lp,t)
                int jn = j + 1;
                int lpn = jn >> 1, tn = jn & 1;
                const uint4* pl = tn ? rp1 : rp0;
                rawb[jn & 1][0] = pl[lpn * 8 + 0];
                rawb[jn & 1][1] = pl[lpn * 8 + 1];
                rawb[jn & 1][2] = pl[lpn * 8 + 4];
                rawb[jn & 1][3] = pl[lpn * 8 + 5];
            }
            int lA = 2 * lp, lB = 2 * lp + 1;
            s16x8 frA[NFRAG], frB[NFRAG];
#pragma unroll
            for (int f = 0; f < NFRAG; f++) {
                frA[f] = __builtin_bit_cast(s16x8, lw[(lA * NFRAG + f) * 64 + lane]);
                frB[f] = __builtin_bit_cast(s16x8, lw[(lB * NFRAG + f) * 64 + lane]);
            }

            s16x8 B1A = bf16pack4(rawb[j & 1][0], rawb[j & 1][1]);
            s16x8 B1B = bf16pack4(rawb[j & 1][2], rawb[j & 1][3]);

            f32x16 z = {0.0f};
            f32x16 dA = __builtin_amdgcn_mfma_f32_32x32x16_bf16(frA[0], B1A, z, 0, 0, 0);
            f32x16 dB = __builtin_amdgcn_mfma_f32_32x32x16_bf16(frB[0], B1B, z, 0, 0, 0);

            s16x8 BaA, BbA, BaB, BbB;
            d_to_b(dA, BaA, BbA);
            d_to_b(dB, BaB, BbB);
            dA = __builtin_amdgcn_mfma_f32_32x32x16_bf16(frA[1], BaA, z, 0, 0, 0);
            dB = __builtin_amdgcn_mfma_f32_32x32x16_bf16(frB[1], BaB, z, 0, 0, 0);
            dA = __builtin_amdgcn_mfma_f32_32x32x16_bf16(frA[2], BbA, dA, 0, 0, 0);
            dB = __builtin_amdgcn_mfma_f32_32x32x16_bf16(frB[2], BbB, dB, 0, 0, 0);

            d_to_b(dA, BaA, BbA);
            d_to_b(dB, BaB, BbB);
            dA = __builtin_amdgcn_mfma_f32_32x32x16_bf16(frA[3], BaA, z, 0, 0, 0);
            dB = __builtin_amdgcn_mfma_f32_32x32x16_bf16(frB[3], BaB, z, 0, 0, 0);
            dA = __builtin_amdgcn_mfma_f32_32x32x16_bf16(frA[4], BbA, dA, 0, 0, 0);
            dB = __builtin_amdgcn_mfma_f32_32x32x16_bf16(frB[4], BbB, dB, 0, 0, 0);

            d_to_b(dA, BaA, BbA);
            d_to_b(dB, BaB, BbB);
            dA = __builtin_amdgcn_mfma_f32_32x32x16_bf16(frA[5], BaA, z, 0, 0, 0);
            dB = __builtin_amdgcn_mfma_f32_32x32x16_bf16(frB[5], BaB, z, 0, 0, 0);
            dA = __builtin_amdgcn_mfma_f32_32x32x16_bf16(frA[6], BbA, dA, 0, 0, 0);
            dB = __builtin_amdgcn_mfma_f32_32x32x16_bf16(frB[6], BbB, dB, 0, 0, 0);

            // two 16-pair batches: stash -> lgkm sync -> full-128B-half-row stores
#pragma unroll
            for (int b = 0; b < 2; b++) {
                if (bh == b) {
                    // lane (col,h) owns feats 4h..4h+3 / 8+4h..11+4h of pair col;
                    // word = li*16 + feat (li: 0 = l even, 1 = l odd)
                    float* swA = scb + pr * SCW + 4 * h;
                    *(f32x4*)swA        = (f32x4){dA[0], dA[1], dA[2], dA[3]};
                    *(f32x4*)(swA + 8)  = (f32x4){dA[4], dA[5], dA[6], dA[7]};
                    float* swB = swA + 16;
                    *(f32x4*)swB        = (f32x4){dB[0], dB[1], dB[2], dB[3]};
                    *(f32x4*)(swB + 8)  = (f32x4){dB[4], dB[5], dB[6], dB[7]};
                }
                asm volatile("s_waitcnt lgkmcnt(0)" ::: "memory");
                __builtin_amdgcn_sched_barrier(0);

                // 2 store instrs; each: 8 lanes cover one FULL 128B half-row
#pragma unroll
                for (int i = 0; i < 2; i++) {
                    int lr = 8 * i + rg;               // 0..15 within batch
                    int r  = 16 * b + lr;
                    int n  = sn[wv][t][r];
                    const float* srd = scb + lr * SCW + 4 * cc;
                    f32x4 v = *(const f32x4*)srd;
                    if (n >= 0)
                        *(f32x4*)((char*)outp + (size_t)n * 256 + (size_t)lp * 128 + cc * 16) = v;
                }
                asm volatile("s_waitcnt lgkmcnt(0)" ::: "memory");
                __builtin_amdgcn_sched_barrier(0);
            }
        }
    } else {
        // ---------- bf16 path (permlane epilogue, frags from LDS) ----------
#pragma unroll
        for (int l = 0; l < L; l++) {
            s16x8 fr[NFRAG];
#pragma unroll
            for (int f = 0; f < NFRAG; f++)
                fr[f] = __builtin_bit_cast(s16x8, lw[(l * NFRAG + f) * 64 + lane]);

#pragma unroll
            for (int t = 0; t < 2; t++) {
                int n = n_t[t];
                int nn = n < 0 ? 0 : n;

                const char* xb = (const char*)rf;
                s16x8 B1 = __builtin_bit_cast(s16x8,
                     *(const uint4*)(xb + (size_t)nn * 128 + l * 32 + h * 16));

                f32x16 z = {0.0f};
                f32x16 d1 = __builtin_amdgcn_mfma_f32_32x32x16_bf16(fr[0], B1, z, 0, 0, 0);

                s16x8 Ba, Bb;
                d_to_b(d1, Ba, Bb);
                f32x16 d2 = __builtin_amdgcn_mfma_f32_32x32x16_bf16(fr[1], Ba, z, 0, 0, 0);
                d2 = __builtin_amdgcn_mfma_f32_32x32x16_bf16(fr[2], Bb, d2, 0, 0, 0);

                d_to_b(d2, Ba, Bb);
                f32x16 d3 = __builtin_amdgcn_mfma_f32_32x32x16_bf16(fr[3], Ba, z, 0, 0, 0);
                d3 = __builtin_amdgcn_mfma_f32_32x32x16_bf16(fr[4], Bb, d3, 0, 0, 0);

                d_to_b(d3, Ba, Bb);
                f32x16 d4 = __builtin_amdgcn_mfma_f32_32x32x16_bf16(fr[5], Ba, z, 0, 0, 0);
                d4 = __builtin_amdgcn_mfma_f32_32x32x16_bf16(fr[6], Bb, d4, 0, 0, 0);

                u32 P[4];
#pragma unroll
                for (int i = 0; i < 4; i++) P[i] = cvt_pk_bf16(d4[2 * i], d4[2 * i + 1]);
                u32x2 r02 = __builtin_amdgcn_permlane32_swap(P[0], P[2], false, false);
                u32x2 r13 = __builtin_amdgcn_permlane32_swap(P[1], P[3], false, false);
                if (n >= 0) {
                    uint4 v = make_uint4(r02[0], r13[0], r02[1], r13[1]);
                    char* ob = (char*)outp;
                    *(uint4*)(ob + (size_t)n * 128 + l * 32 + h * 16) = v;
                }
            }
        }
    }
}

extern "C" void kernel_launch(void* const* d_in, const int* in_sizes, int n_in,
                              void* d_out, int out_size, void* d_ws, size_t ws_size,
                              hipStream_t stream) {
    const void* rf     = d_in[0];
    const int* species = (const int*)d_in[1];
    const void* W1     = d_in[2];
    const void* W2     = d_in[3];
    const void* W3     = d_in[4];
    const void* W4     = d_in[5];

    int N = in_sizes[1];
    int* hdr   = (int*)d_ws;
    uint4* wf  = (uint4*)((char*)d_ws + 256);
    int* perm  = (int*)d_ws + WS_PERM_INT;

    int nb4   = (N + BLK * 4 - 1) / (BLK * 4);
    int nwp   = (WF_ENTRIES + BLK - 1) / BLK;
    int grid4 = (N + S * (BLK4 - 1) + BLK4 - 1) / BLK4;

    k_wprep   <<<dim3(nwp),  dim3(BLK),  0, stream>>>(W1, W2, W3, W4,
                                                      (const u32*)rf, hdr, wf);
    k1_hist   <<<dim3(nb4),  dim3(BLK),  0, stream>>>(species, hdr, N);
    k3_scatter<<<dim3(nb4),  dim3(BLK),  0, stream>>>(species, hdr, perm, N);
    k4_mlp    <<<dim3(grid4),dim3(BLK4), 0, stream>>>(rf, hdr, perm, wf, d_out);
}

// Round 8
// 277.148 us; speedup vs baseline: 1.0002x; 1.0002x over previous
//
#include <hip/hip_runtime.h>
#include <stdint.h>

typedef unsigned int u32;
typedef unsigned long long u64;

constexpr int L   = 4;
constexpr int S   = 4;
constexpr int NM  = 16;
constexpr int HID = 32;
constexpr int BLK = 256;
constexpr int NFRAG = 7;                       // A-frags per (l,s): L1:1, L2:2, L3:2, L4:2
constexpr int WF_ENTRIES = L * S * NFRAG * 64; // 7168 uint4 entries
constexpr int WS_PERM_INT = (256 + WF_ENTRIES * 16) / 4;  // perm after hdr+wfrag

typedef short  s16x8  __attribute__((ext_vector_type(8)));
typedef float  f32x16 __attribute__((ext_vector_type(16)));
typedef float  f32x4  __attribute__((ext_vector_type(4)));
typedef unsigned int u32x2 __attribute__((ext_vector_type(2)));

// ws: [0,64B) hdr ints: [0..3] counts (k1), [4..7] scatter cursors (k3).
// wfrag uint4 at byte 256. perm at int WS_PERM_INT.

__device__ __forceinline__ int load_species(const int* sp, int i64, int n) {
    return i64 ? sp[2 * n] : sp[n];
}

// Pre-swizzle weights into 32x32x16 A-fragment order (transposed: A[m=out][k=in]).
// Entry e = ((l*S+s)*NFRAG + f)*64 + lane. Lane holds k = 8*(lane>>5)+j, m = lane&31.
// Block 0 also zeroes hdr[0..8] (stream-ordered before k1_hist/k3_scatter).
__global__ void k_wprep(const void* __restrict__ W1, const void* __restrict__ W2,
                        const void* __restrict__ W3, const void* __restrict__ W4,
                        const u32* __restrict__ rfw, int* __restrict__ hdr,
                        uint4* __restrict__ wf) {
    __shared__ int sf32;
    int tid = threadIdx.x;
    if (tid < 64) {
        u32 w  = rfw[tid];
        u32 lo = w & 0xffffu;
        u32 ex = (lo >> 7) & 0xffu;
        int plausible = (lo == 0u || (ex >= 90u && ex <= 141u)) ? 1 : 0;
        u64 pm = __ballot(plausible);
        if (tid == 0) sf32 = (__popcll(pm) < 48) ? 1 : 0;   // fp32 inputs
    }
    if (blockIdx.x == 0 && tid < 9) hdr[tid] = 0;
    __syncthreads();
    int isf32 = sf32;

    int e = blockIdx.x * BLK + tid;
    if (e >= WF_ENTRIES) return;
    int lam = e & 63;
    int f   = (e >> 6) % NFRAG;
    int ls  = e / (64 * NFRAG);
    int m = lam & 31, h = lam >> 5;
    unsigned short vals[8];
#pragma unroll
    for (int j = 0; j < 8; j++) {
        int k = 8 * h + j;
        const void* base; size_t off; bool zero = false;
        if (f == 0)      { base = W1; off = (size_t)ls * 512  + (size_t)k * 32 + m; }
        else if (f <= 2) { base = W2; off = (size_t)ls * 1024 + (size_t)(k + 16 * (f - 1)) * 32 + m; }
        else if (f <= 4) { base = W3; off = (size_t)ls * 1024 + (size_t)(k + 16 * (f - 3)) * 32 + m; }
        else             { zero = (m >= NM); base = W4;
                           off = (size_t)ls * 512 + (size_t)(k + 16 * (f - 5)) * NM + (m & 15); }
        unsigned short v;
        if (zero) v = 0;
        else if (isf32) {
            u32 u = __float_as_uint(((const float*)base)[off]);
            u32 r = ((u >> 16) & 1u) + 0x7fffu;
            v = (unsigned short)((u + r) >> 16);
        } else v = ((const unsigned short*)base)[off];
        vals[j] = v;
    }
    uint4 q;
    q.x = vals[0] | ((u32)vals[1] << 16);
    q.y = vals[2] | ((u32)vals[3] << 16);
    q.z = vals[4] | ((u32)vals[5] << 16);
    q.w = vals[6] | ((u32)vals[7] << 16);
    wf[e] = q;
}

// 4 elems/thread histogram: 489 blocks, 4 global atomics/block.
__global__ void k1_hist(const int* __restrict__ sp, int* __restrict__ hdr, int N) {
    __shared__ int cnt[S];
    __shared__ int si64;
    int t = threadIdx.x;
    if (t < 64) {
        u64 om = __ballot(((const u32*)sp)[2 * t + 1] != 0u);
        if (t == 0) si64 = (om == 0ull) ? 1 : 0;
    }
    if (t < S) cnt[t] = 0;
    __syncthreads();
    int i64 = si64;
    int base = blockIdx.x * (BLK * 4) + t * 4;
    if (base + 3 < N) {
        int s0, s1, s2, s3;
        if (i64) {
            int4 a = ((const int4*)sp)[base / 2];
            int4 b = ((const int4*)sp)[base / 2 + 1];
            s0 = a.x; s1 = a.z; s2 = b.x; s3 = b.z;
        } else {
            int4 a = ((const int4*)sp)[base / 4];
            s0 = a.x; s1 = a.y; s2 = a.z; s3 = a.w;
        }
        atomicAdd(&cnt[s0], 1); atomicAdd(&cnt[s1], 1);
        atomicAdd(&cnt[s2], 1); atomicAdd(&cnt[s3], 1);
    } else {
        for (int k = 0; k < 4; k++) {
            int n = base + k;
            if (n < N) atomicAdd(&cnt[load_species(sp, i64, n)], 1);
        }
    }
    __syncthreads();
    if (t < S) atomicAdd(&hdr[t], cnt[t]);
}

// 4 elems/thread scatter: block-local ranks, one cursor bump/species/block.
__global__ void k3_scatter(const int* __restrict__ sp, int* __restrict__ hdr,
                           int* __restrict__ perm, int N) {
    __shared__ int cnt[S];
    __shared__ int base[S];
    __shared__ int bp[S + 1];
    __shared__ int cs[S];
    __shared__ int si64;
    int t = threadIdx.x;
    if (t < 64) {
        u64 om = __ballot(((const u32*)sp)[2 * t + 1] != 0u);
        if (t == 0) si64 = (om == 0ull) ? 1 : 0;
    }
    if (t == 0) {
        int acc = 0;
        for (int q = 0; q < S; q++) {
            cs[q] = hdr[q];
            bp[q] = acc;
            acc += (cs[q] + BLK - 1) & ~(BLK - 1);
        }
        bp[S] = acc;
    }
    if (t < S) cnt[t] = 0;
    __syncthreads();
    int i64 = si64;
    int nb0 = blockIdx.x * (BLK * 4) + t * 4;
    int s_[4], r_[4];
    bool v_[4];
    if (nb0 + 3 < N) {
        if (i64) {
            int4 a = ((const int4*)sp)[nb0 / 2];
            int4 b = ((const int4*)sp)[nb0 / 2 + 1];
            s_[0] = a.x; s_[1] = a.z; s_[2] = b.x; s_[3] = b.z;
        } else {
            int4 a = ((const int4*)sp)[nb0 / 4];
            s_[0] = a.x; s_[1] = a.y; s_[2] = a.z; s_[3] = a.w;
        }
        v_[0] = v_[1] = v_[2] = v_[3] = true;
    } else {
        for (int k = 0; k < 4; k++) {
            int n = nb0 + k;
            v_[k] = (n < N);
            s_[k] = v_[k] ? load_species(sp, i64, n) : 0;
        }
    }
#pragma unroll
    for (int k = 0; k < 4; k++)
        if (v_[k]) r_[k] = atomicAdd(&cnt[s_[k]], 1);
    __syncthreads();
    if (t < S) base[t] = bp[t] + atomicAdd(&hdr[4 + t], cnt[t]);
    __syncthreads();
#pragma unroll
    for (int k = 0; k < 4; k++)
        if (v_[k]) perm[base[s_[k]] + r_[k]] = nb0 + k;
    if (blockIdx.x == 0) {
        for (int q = 0; q < S; q++)
            for (int i = bp[q] + cs[q] + t; i < bp[q + 1]; i += BLK) perm[i] = -1;
    }
}

// packed fp32->bf16 (RNE) — single instruction; tolerance 0.125 >> RNE/half-up delta
__device__ __forceinline__ u32 cvt_pk_bf16(float a, float b) {
    u32 r;
    asm("v_cvt_pk_bf16_f32 %0, %1, %2" : "=v"(r) : "v"(a), "v"(b));
    return r;
}

__device__ __forceinline__ float silu(float v) {
    float e = __expf(-v);
    return v * __builtin_amdgcn_rcpf(1.0f + e);
}

// D (C/D layout) -> next-layer B frags (Ba: k=0..15, Bb: k=16..31), with SiLU.
// Cross-half exchange via v_permlane32_swap; packs via v_cvt_pk_bf16_f32.
__device__ __forceinline__ void d_to_b(const f32x16& d, s16x8& Ba, s16x8& Bb) {
    u32 P[8];
#pragma unroll
    for (int i = 0; i < 8; i++)
        P[i] = cvt_pk_bf16(silu(d[2 * i]), silu(d[2 * i + 1]));
    u32x2 r02 = __builtin_amdgcn_permlane32_swap(P[0], P[2], false, false);
    u32x2 r13 = __builtin_amdgcn_permlane32_swap(P[1], P[3], false, false);
    u32x2 r46 = __builtin_amdgcn_permlane32_swap(P[4], P[6], false, false);
    u32x2 r57 = __builtin_amdgcn_permlane32_swap(P[5], P[7], false, false);
    Ba = __builtin_bit_cast(s16x8, make_uint4(r02[0], r13[0], r02[1], r13[1]));
    Bb = __builtin_bit_cast(s16x8, make_uint4(r46[0], r57[0], r46[1], r57[1]));
}

__device__ __forceinline__ s16x8 bf16pack4(uint4 q0, uint4 q1) {
    u32 w0 = cvt_pk_bf16(__uint_as_float(q0.x), __uint_as_float(q0.y));
    u32 w1 = cvt_pk_bf16(__uint_as_float(q0.z), __uint_as_float(q0.w));
    u32 w2 = cvt_pk_bf16(__uint_as_float(q1.x), __uint_as_float(q1.y));
    u32 w3 = cvt_pk_bf16(__uint_as_float(q1.z), __uint_as_float(q1.w));
    return __builtin_bit_cast(s16x8, make_uint4(w0, w1, w2, w3));
}

// Per-wave half-row scratch stride: 32 data words + 4 pad. 16 pairs per batch.
constexpr int SCW = 36;

// Block = 256 pairs x ONE l-pair (lp). LDS: 14336 (lw) + 9216 (sc) + 1024 (sn)
// ~= 24.6 KB -> 6 blocks/CU = 24 waves/CU (was 16). bx = 2*pb + lp keeps the
// two 128B halves of each output row temporally adjacent.
__global__ __launch_bounds__(BLK, 6) void k4_mlp(
    const void* __restrict__ rf, const int* __restrict__ hdr,
    const int* __restrict__ perm, const uint4* __restrict__ wf,
    void* __restrict__ outp)
{
    __shared__ uint4 lw[2 * NFRAG * 64];     // 14336 B: this block's l-pair frags
    __shared__ float sc[4][16 * SCW];        // 9216 B: per-wave 16-pair scratch
    __shared__ int   sn[4][2][32];           // 1024 B: per-wave pair indices
    __shared__ int   sf32;

    int tid = threadIdx.x;
    int pb  = blockIdx.x >> 1;               // pair-chunk index
    int lp  = blockIdx.x & 1;                // l-pair: {0,1} or {2,3}

    // bases from counts (padded prefix)
    int c0 = hdr[0], c1 = hdr[1], c2 = hdr[2], c3 = hdr[3];
    int b1 = (c0 + BLK - 1) & ~(BLK - 1);
    int b2 = b1 + ((c1 + BLK - 1) & ~(BLK - 1));
    int b3 = b2 + ((c2 + BLK - 1) & ~(BLK - 1));
    int b4 = b3 + ((c3 + BLK - 1) & ~(BLK - 1));
    int p0 = pb * BLK;
    if (p0 >= b4) return;                    // uniform: whole block exits
    int s = (p0 >= b3) ? 3 : ((p0 >= b2) ? 2 : ((p0 >= b1) ? 1 : 0));
    s = __builtin_amdgcn_readfirstlane(s);

    if (tid < 64) {                          // inline fp32 detect (256B broadcast)
        u32 w  = ((const u32*)rf)[tid];
        u32 lo = w & 0xffffu;
        u32 ex = (lo >> 7) & 0xffu;
        int plausible = (lo == 0u || (ex >= 90u && ex <= 141u)) ? 1 : 0;
        u64 pm = __ballot(plausible);
        if (tid == 0) sf32 = (__popcll(pm) < 48) ? 1 : 0;
    }

    // stage this l-pair's weight frags to LDS (896 entries)
#pragma unroll
    for (int c = 0; c < 4; c++) {
        int idx = tid + c * BLK;             // < 1024
        if (idx < 2 * NFRAG * 64) {
            int l2 = idx / (NFRAG * 64);
            int r  = idx - l2 * (NFRAG * 64);
            int l  = lp * 2 + l2;
            lw[idx] = wf[(size_t)((l * S + s) * NFRAG) * 64 + r];
        }
    }

    int wv   = tid >> 6;
    int lane = tid & 63;
    int col  = lane & 31;
    int h    = lane >> 5;

    int n_t[2];
#pragma unroll
    for (int t = 0; t < 2; t++) {
        n_t[t] = perm[p0 + wv * 64 + t * 32 + col];
        sn[wv][t][col] = n_t[t];
    }
    __syncthreads();
    int isf32 = sf32;

    if (isf32) {
        // ---- fp32: t loop, TWO independent l-chains interleaved (2x ILP),
        //      128B half-row stores via 16-pair LDS transpose batches ----
        const char* xb = (const char*)rf;
        int nn0 = n_t[0] < 0 ? 0 : n_t[0];
        int nn1 = n_t[1] < 0 ? 0 : n_t[1];
        const uint4* rp0 = (const uint4*)(xb + (size_t)nn0 * 256 + lp * 128 + h * 32);
        const uint4* rp1 = (const uint4*)(xb + (size_t)nn1 * 256 + lp * 128 + h * 32);

        int rg = lane >> 3;                  // 0..7: half-row group for stores
        int cc = lane & 7;                   // 0..7: 16B chunk within a 128B half-row
        int bh = col >> 4;                   // which 16-pair batch this lane's data is in
        int pr = col & 15;                   // pair index within batch
        float* scb = &sc[wv][0];

        // double-buffered input rows: rawb[t][li*2 + half]
        uint4 rawb[2][4];
        rawb[0][0] = rp0[0]; rawb[0][1] = rp0[1];   // li=0
        rawb[0][2] = rp0[4]; rawb[0][3] = rp0[5];   // li=1

#pragma unroll
        for (int t = 0; t < 2; t++) {
            if (t == 0) {                            // prefetch t=1
                rawb[1][0] = rp1[0]; rawb[1][1] = rp1[1];
                rawb[1][2] = rp1[4]; rawb[1][3] = rp1[5];
            }
            s16x8 frA[NFRAG], frB[NFRAG];
#pragma unroll
            for (int f = 0; f < NFRAG; f++) {
                frA[f] = __builtin_bit_cast(s16x8, lw[(0 * NFRAG + f) * 64 + lane]);
                frB[f] = __builtin_bit_cast(s16x8, lw[(1 * NFRAG + f) * 64 + lane]);
            }

            s16x8 B1A = bf16pack4(rawb[t][0], rawb[t][1]);
            s16x8 B1B = bf16pack4(rawb[t][2], rawb[t][3]);

            f32x16 z = {0.0f};
            f32x16 dA = __builtin_amdgcn_mfma_f32_32x32x16_bf16(frA[0], B1A, z, 0, 0, 0);
            f32x16 dB = __builtin_amdgcn_mfma_f32_32x32x16_bf16(frB[0], B1B, z, 0, 0, 0);

            s16x8 BaA, BbA, BaB, BbB;
            d_to_b(dA, BaA, BbA);
            d_to_b(dB, BaB, BbB);
            dA = __builtin_amdgcn_mfma_f32_32x32x16_bf16(frA[1], BaA, z, 0, 0, 0);
            dB = __builtin_amdgcn_mfma_f32_32x32x16_bf16(frB[1], BaB, z, 0, 0, 0);
            dA = __builtin_amdgcn_mfma_f32_32x32x16_bf16(frA[2], BbA, dA, 0, 0, 0);
            dB = __builtin_amdgcn_mfma_f32_32x32x16_bf16(frB[2], BbB, dB, 0, 0, 0);

            d_to_b(dA, BaA, BbA);
            d_to_b(dB, BaB, BbB);
            dA = __builtin_amdgcn_mfma_f32_32x32x16_bf16(frA[3], BaA, z, 0, 0, 0);
            dB = __builtin_amdgcn_mfma_f32_32x32x16_bf16(frB[3], BaB, z, 0, 0, 0);
            dA = __builtin_amdgcn_mfma_f32_32x32x16_bf16(frA[4], BbA, dA, 0, 0, 0);
            dB = __builtin_amdgcn_mfma_f32_32x32x16_bf16(frB[4], BbB, dB, 0, 0, 0);

            d_to_b(dA, BaA, BbA);
            d_to_b(dB, BaB, BbB);
            dA = __builtin_amdgcn_mfma_f32_32x32x16_bf16(frA[5], BaA, z, 0, 0, 0);
            dB = __builtin_amdgcn_mfma_f32_32x32x16_bf16(frB[5], BaB, z, 0, 0, 0);
            dA = __builtin_amdgcn_mfma_f32_32x32x16_bf16(frA[6], BbA, dA, 0, 0, 0);
            dB = __builtin_amdgcn_mfma_f32_32x32x16_bf16(frB[6], BbB, dB, 0, 0, 0);

            // two 16-pair batches: stash -> lgkm sync -> full-128B-half-row stores
#pragma unroll
            for (int b = 0; b < 2; b++) {
                if (bh == b) {
                    // lane (col,h) owns feats 4h..4h+3 / 8+4h..11+4h of pair col;
                    // word = li*16 + feat (li: 0 = l even, 1 = l odd)
                    float* swA = scb + pr * SCW + 4 * h;
                    *(f32x4*)swA        = (f32x4){dA[0], dA[1], dA[2], dA[3]};
                    *(f32x4*)(swA + 8)  = (f32x4){dA[4], dA[5], dA[6], dA[7]};
                    float* swB = swA + 16;
                    *(f32x4*)swB        = (f32x4){dB[0], dB[1], dB[2], dB[3]};
                    *(f32x4*)(swB + 8)  = (f32x4){dB[4], dB[5], dB[6], dB[7]};
                }
                asm volatile("s_waitcnt lgkmcnt(0)" ::: "memory");
                __builtin_amdgcn_sched_barrier(0);

                // 2 store instrs; each: 8 lanes cover one FULL 128B half-row
#pragma unroll
                for (int i = 0; i < 2; i++) {
                    int lr = 8 * i + rg;               // 0..15 within batch
                    int r  = 16 * b + lr;
                    int n  = sn[wv][t][r];
                    const float* srd = scb + lr * SCW + 4 * cc;
                    f32x4 v = *(const f32x4*)srd;
                    if (n >= 0)
                        *(f32x4*)((char*)outp + (size_t)n * 256 + (size_t)lp * 128 + cc * 16) = v;
                }
                asm volatile("s_waitcnt lgkmcnt(0)" ::: "memory");
                __builtin_amdgcn_sched_barrier(0);
            }
        }
    } else {
        // ---------- bf16 path (this block's 2 l's; permlane epilogue) ----------
#pragma unroll
        for (int l2 = 0; l2 < 2; l2++) {
            int l = lp * 2 + l2;
            s16x8 fr[NFRAG];
#pragma unroll
            for (int f = 0; f < NFRAG; f++)
                fr[f] = __builtin_bit_cast(s16x8, lw[(l2 * NFRAG + f) * 64 + lane]);

#pragma unroll
            for (int t = 0; t < 2; t++) {
                int n = n_t[t];
                int nn = n < 0 ? 0 : n;

                const char* xb = (const char*)rf;
                s16x8 B1 = __builtin_bit_cast(s16x8,
                     *(const uint4*)(xb + (size_t)nn * 128 + l * 32 + h * 16));

                f32x16 z = {0.0f};
                f32x16 d1 = __builtin_amdgcn_mfma_f32_32x32x16_bf16(fr[0], B1, z, 0, 0, 0);

                s16x8 Ba, Bb;
                d_to_b(d1, Ba, Bb);
                f32x16 d2 = __builtin_amdgcn_mfma_f32_32x32x16_bf16(fr[1], Ba, z, 0, 0, 0);
                d2 = __builtin_amdgcn_mfma_f32_32x32x16_bf16(fr[2], Bb, d2, 0, 0, 0);

                d_to_b(d2, Ba, Bb);
                f32x16 d3 = __builtin_amdgcn_mfma_f32_32x32x16_bf16(fr[3], Ba, z, 0, 0, 0);
                d3 = __builtin_amdgcn_mfma_f32_32x32x16_bf16(fr[4], Bb, d3, 0, 0, 0);

                d_to_b(d3, Ba, Bb);
                f32x16 d4 = __builtin_amdgcn_mfma_f32_32x32x16_bf16(fr[5], Ba, z, 0, 0, 0);
                d4 = __builtin_amdgcn_mfma_f32_32x32x16_bf16(fr[6], Bb, d4, 0, 0, 0);

                u32 P[4];
#pragma unroll
                for (int i = 0; i < 4; i++) P[i] = cvt_pk_bf16(d4[2 * i], d4[2 * i + 1]);
                u32x2 r02 = __builtin_amdgcn_permlane32_swap(P[0], P[2], false, false);
                u32x2 r13 = __builtin_amdgcn_permlane32_swap(P[1], P[3], false, false);
                if (n >= 0) {
                    uint4 v = make_uint4(r02[0], r13[0], r02[1], r13[1]);
                    char* ob = (char*)outp;
                    *(uint4*)(ob + (size_t)n * 128 + l * 32 + h * 16) = v;
                }
            }
        }
    }
}

extern "C" void kernel_launch(void* const* d_in, const int* in_sizes, int n_in,
                              void* d_out, int out_size, void* d_ws, size_t ws_size,
                              hipStream_t stream) {
    const void* rf     = d_in[0];
    const int* species = (const int*)d_in[1];
    const void* W1     = d_in[2];
    const void* W2     = d_in[3];
    const void* W3     = d_in[4];
    const void* W4     = d_in[5];

    int N = in_sizes[1];
    int* hdr   = (int*)d_ws;
    uint4* wf  = (uint4*)((char*)d_ws + 256);
    int* perm  = (int*)d_ws + WS_PERM_INT;

    int nb4   = (N + BLK * 4 - 1) / (BLK * 4);
    int nwp   = (WF_ENTRIES + BLK - 1) / BLK;
    int nbp   = (N + S * (BLK - 1) + BLK - 1) / BLK;   // padded pair-chunks
    int grid4 = 2 * nbp;                               // x2: l-pair split

    k_wprep   <<<dim3(nwp),  dim3(BLK), 0, stream>>>(W1, W2, W3, W4,
                                                     (const u32*)rf, hdr, wf);
    k1_hist   <<<dim3(nb4),  dim3(BLK), 0, stream>>>(species, hdr, N);
    k3_scatter<<<dim3(nb4),  dim3(BLK), 0, stream>>>(species, hdr, perm, N);
    k4_mlp    <<<dim3(grid4),dim3(BLK), 0, stream>>>(rf, hdr, perm, wf, d_out);
}

// Round 11
// 269.711 us; speedup vs baseline: 1.0278x; 1.0276x over previous
//
#include <hip/hip_runtime.h>
#include <stdint.h>

typedef unsigned int u32;
typedef unsigned long long u64;

constexpr int L   = 4;
constexpr int S   = 4;
constexpr int NM  = 16;
constexpr int HID = 32;
constexpr int BLK = 256;
constexpr int NFRAG = 7;                       // A-frags per (l,s): L1:1, L2:2, L3:2, L4:2
constexpr int WF_ENTRIES = L * S * NFRAG * 64; // 7168 uint4 entries
constexpr int WS_PERM_INT = (256 + WF_ENTRIES * 16) / 4;  // perm after hdr+wfrag

typedef short  s16x8  __attribute__((ext_vector_type(8)));
typedef float  f32x16 __attribute__((ext_vector_type(16)));
typedef float  f32x4  __attribute__((ext_vector_type(4)));
typedef unsigned int u32x2 __attribute__((ext_vector_type(2)));

// ws: [0,64B) hdr ints: [0..3] species totals (written by k2).
// wfrag uint4 at byte 256. perm at int WS_PERM_INT (N + S*BLK ints).
// bbase (per-block stable bases, S*NB ints) lives in the TAIL OF d_out:
// produced by k1, dead before k4 launches; k4 overwrites all of d_out.
// (Workspace footprint identical to the last known-good run.)

__device__ __forceinline__ int load_species(const int* sp, int i64, int n) {
    return i64 ? sp[2 * n] : sp[n];
}

// Pre-swizzle weights into 32x32x16 A-fragment order (transposed: A[m=out][k=in]).
// Entry e = ((l*S+s)*NFRAG + f)*64 + lane. Lane holds k = 8*(lane>>5)+j, m = lane&31.
__global__ void k_wprep(const void* __restrict__ W1, const void* __restrict__ W2,
                        const void* __restrict__ W3, const void* __restrict__ W4,
                        const u32* __restrict__ rfw, int* __restrict__ hdr,
                        uint4* __restrict__ wf) {
    __shared__ int sf32;
    int tid = threadIdx.x;
    if (tid < 64) {
        u32 w  = rfw[tid];
        u32 lo = w & 0xffffu;
        u32 ex = (lo >> 7) & 0xffu;
        int plausible = (lo == 0u || (ex >= 90u && ex <= 141u)) ? 1 : 0;
        u64 pm = __ballot(plausible);
        if (tid == 0) sf32 = (__popcll(pm) < 48) ? 1 : 0;   // fp32 inputs
    }
    if (blockIdx.x == 0 && tid < 9) hdr[tid] = 0;
    __syncthreads();
    int isf32 = sf32;

    int e = blockIdx.x * BLK + tid;
    if (e >= WF_ENTRIES) return;
    int lam = e & 63;
    int f   = (e >> 6) % NFRAG;
    int ls  = e / (64 * NFRAG);
    int m = lam & 31, h = lam >> 5;
    unsigned short vals[8];
#pragma unroll
    for (int j = 0; j < 8; j++) {
        int k = 8 * h + j;
        const void* base; size_t off; bool zero = false;
        if (f == 0)      { base = W1; off = (size_t)ls * 512  + (size_t)k * 32 + m; }
        else if (f <= 2) { base = W2; off = (size_t)ls * 1024 + (size_t)(k + 16 * (f - 1)) * 32 + m; }
        else if (f <= 4) { base = W3; off = (size_t)ls * 1024 + (size_t)(k + 16 * (f - 3)) * 32 + m; }
        else             { zero = (m >= NM); base = W4;
                           off = (size_t)ls * 512 + (size_t)(k + 16 * (f - 5)) * NM + (m & 15); }
        unsigned short v;
        if (zero) v = 0;
        else if (isf32) {
            u32 u = __float_as_uint(((const float*)base)[off]);
            u32 r = ((u >> 16) & 1u) + 0x7fffu;
            v = (unsigned short)((u + r) >> 16);
        } else v = ((const unsigned short*)base)[off];
        vals[j] = v;
    }
    uint4 q;
    q.x = vals[0] | ((u32)vals[1] << 16);
    q.y = vals[2] | ((u32)vals[3] << 16);
    q.z = vals[4] | ((u32)vals[5] << 16);
    q.w = vals[6] | ((u32)vals[7] << 16);
    wf[e] = q;
}

// Per-block species counts (4 elems/thread). No global atomics.
__global__ void k1_hist(const int* __restrict__ sp, int* __restrict__ bcnt,
                        int N, int NB) {
    __shared__ int cnt[S];
    __shared__ int si64;
    int t = threadIdx.x;
    if (t < 64) {
        u64 om = __ballot(((const u32*)sp)[2 * t + 1] != 0u);
        if (t == 0) si64 = (om == 0ull) ? 1 : 0;
    }
    if (t < S) cnt[t] = 0;
    __syncthreads();
    int i64 = si64;
    int base = blockIdx.x * (BLK * 4) + t * 4;
    if (base + 3 < N) {
        int s0, s1, s2, s3;
        if (i64) {
            int4 a = ((const int4*)sp)[base / 2];
            int4 b = ((const int4*)sp)[base / 2 + 1];
            s0 = a.x; s1 = a.z; s2 = b.x; s3 = b.z;
        } else {
            int4 a = ((const int4*)sp)[base / 4];
            s0 = a.x; s1 = a.y; s2 = a.z; s3 = a.w;
        }
        atomicAdd(&cnt[s0], 1); atomicAdd(&cnt[s1], 1);
        atomicAdd(&cnt[s2], 1); atomicAdd(&cnt[s3], 1);
    } else {
        for (int k = 0; k < 4; k++) {
            int n = base + k;
            if (n < N) atomicAdd(&cnt[load_species(sp, i64, n)], 1);
        }
    }
    __syncthreads();
    if (t < S) bcnt[t * NB + blockIdx.x] = cnt[t];
}

// Exclusive scan of per-block counts per species -> absolute stable bases.
// 1 block, 256 threads: wave w scans species w; then add padded region bases.
__global__ void k2_scan(int* __restrict__ hdr, int* __restrict__ bbase, int NB) {
    int t = threadIdx.x, wv = t >> 6, lane = t & 63;
    if (wv < S) {
        int carry = 0;
        for (int c0 = 0; c0 < NB; c0 += 64) {
            int b = c0 + lane;
            int own = (b < NB) ? bbase[wv * NB + b] : 0;
            int x = own;
#pragma unroll
            for (int o = 1; o < 64; o <<= 1) {
                int v = __shfl_up(x, o, 64);
                if (lane >= o) x += v;
            }
            if (b < NB) bbase[wv * NB + b] = carry + x - own;  // exclusive local prefix
            carry += __shfl(x, 63, 64);
        }
        if (lane == 0) hdr[wv] = carry;                        // species total
    }
    __syncthreads();
    int c0 = hdr[0], c1 = hdr[1], c2 = hdr[2];
    int rb1 = (c0 + BLK - 1) & ~(BLK - 1);
    int rb2 = rb1 + ((c1 + BLK - 1) & ~(BLK - 1));
    int rb3 = rb2 + ((c2 + BLK - 1) & ~(BLK - 1));
    for (int i = t; i < S * NB; i += 256) {
        int s = i / NB;
        int rb = (s == 0) ? 0 : ((s == 1) ? rb1 : ((s == 2) ? rb2 : rb3));
        bbase[i] += rb;
    }
}

// Stable scatter: perm ascending within each species region (sequential HBM in k4).
__global__ void k3_scatter(const int* __restrict__ sp, const int* __restrict__ hdr,
                           const int* __restrict__ bbase, int* __restrict__ perm,
                           int N, int NB) {
    __shared__ int wt01[4], wt23[4];
    __shared__ int sbase[S];
    __shared__ int bp[S + 1];
    __shared__ int cs[S];
    __shared__ int si64;
    int t = threadIdx.x, wv = t >> 6, lane = t & 63;
    if (t < 64) {
        u64 om = __ballot(((const u32*)sp)[2 * t + 1] != 0u);
        if (t == 0) si64 = (om == 0ull) ? 1 : 0;
    }
    if (t == 0) {
        int acc = 0;
        for (int q = 0; q < S; q++) {
            cs[q] = hdr[q];
            bp[q] = acc;
            acc += (cs[q] + BLK - 1) & ~(BLK - 1);
        }
        bp[S] = acc;
    }
    if (t < S) sbase[t] = bbase[t * NB + blockIdx.x];
    __syncthreads();
    int i64 = si64;
    int nb0 = blockIdx.x * (BLK * 4) + t * 4;
    int s_[4];
    bool v_[4];
    if (nb0 + 3 < N) {
        if (i64) {
            int4 a = ((const int4*)sp)[nb0 / 2];
            int4 b = ((const int4*)sp)[nb0 / 2 + 1];
            s_[0] = a.x; s_[1] = a.z; s_[2] = b.x; s_[3] = b.z;
        } else {
            int4 a = ((const int4*)sp)[nb0 / 4];
            s_[0] = a.x; s_[1] = a.y; s_[2] = a.z; s_[3] = a.w;
        }
        v_[0] = v_[1] = v_[2] = v_[3] = true;
    } else {
        for (int k = 0; k < 4; k++) {
            int n = nb0 + k;
            v_[k] = (n < N);
            s_[k] = v_[k] ? load_species(sp, i64, n) : 0;
        }
    }
    // packed per-thread counts: p01 = c0 | c1<<16, p23 = c2 | c3<<16
    int own01 = 0, own23 = 0;
#pragma unroll
    for (int k = 0; k < 4; k++) {
        if (v_[k]) {
            if (s_[k] < 2) own01 += 1 << (16 * s_[k]);
            else           own23 += 1 << (16 * (s_[k] - 2));
        }
    }
    int p01 = own01, p23 = own23;
#pragma unroll
    for (int o = 1; o < 64; o <<= 1) {
        int v0 = __shfl_up(p01, o, 64);
        int v1 = __shfl_up(p23, o, 64);
        if (lane >= o) { p01 += v0; p23 += v1; }
    }
    if (lane == 63) { wt01[wv] = p01; wt23[wv] = p23; }
    __syncthreads();
    int cw01 = 0, cw23 = 0;
    for (int w = 0; w < wv; w++) { cw01 += wt01[w]; cw23 += wt23[w]; }
    int e01 = cw01 + p01 - own01;   // exclusive packed prefix for this thread
    int e23 = cw23 + p23 - own23;
    int o0 = e01 & 0xffff, o1 = (e01 >> 16) & 0xffff;
    int o2 = e23 & 0xffff, o3 = (e23 >> 16) & 0xffff;
#pragma unroll
    for (int k = 0; k < 4; k++) {
        if (v_[k]) {
            int s = s_[k];
            int off = (s == 0) ? o0 : ((s == 1) ? o1 : ((s == 2) ? o2 : o3));
            int sb  = (s == 0) ? sbase[0] : ((s == 1) ? sbase[1]
                      : ((s == 2) ? sbase[2] : sbase[3]));
            perm[sb + off] = nb0 + k;
            o0 += (s == 0); o1 += (s == 1); o2 += (s == 2); o3 += (s == 3);
        }
    }
    if (blockIdx.x == 0) {
        for (int q = 0; q < S; q++)
            for (int i = bp[q] + cs[q] + t; i < bp[q + 1]; i += BLK) perm[i] = -1;
    }
}

// packed fp32->bf16 (RNE) — single instruction; tolerance 0.125 >> RNE/half-up delta
__device__ __forceinline__ u32 cvt_pk_bf16(float a, float b) {
    u32 r;
    asm("v_cvt_pk_bf16_f32 %0, %1, %2" : "=v"(r) : "v"(a), "v"(b));
    return r;
}

__device__ __forceinline__ float silu(float v) {
    float e = __expf(-v);
    return v * __builtin_amdgcn_rcpf(1.0f + e);
}

// D (C/D layout) -> next-layer B frags (Ba: k=0..15, Bb: k=16..31), with SiLU.
// Cross-half exchange via v_permlane32_swap; packs via v_cvt_pk_bf16_f32.
__device__ __forceinline__ void d_to_b(const f32x16& d, s16x8& Ba, s16x8& Bb) {
    u32 P[8];
#pragma unroll
    for (int i = 0; i < 8; i++)
        P[i] = cvt_pk_bf16(silu(d[2 * i]), silu(d[2 * i + 1]));
    u32x2 r02 = __builtin_amdgcn_permlane32_swap(P[0], P[2], false, false);
    u32x2 r13 = __builtin_amdgcn_permlane32_swap(P[1], P[3], false, false);
    u32x2 r46 = __builtin_amdgcn_permlane32_swap(P[4], P[6], false, false);
    u32x2 r57 = __builtin_amdgcn_permlane32_swap(P[5], P[7], false, false);
    Ba = __builtin_bit_cast(s16x8, make_uint4(r02[0], r13[0], r02[1], r13[1]));
    Bb = __builtin_bit_cast(s16x8, make_uint4(r46[0], r57[0], r46[1], r57[1]));
}

__device__ __forceinline__ s16x8 bf16pack4(uint4 q0, uint4 q1) {
    u32 w0 = cvt_pk_bf16(__uint_as_float(q0.x), __uint_as_float(q0.y));
    u32 w1 = cvt_pk_bf16(__uint_as_float(q0.z), __uint_as_float(q0.w));
    u32 w2 = cvt_pk_bf16(__uint_as_float(q1.x), __uint_as_float(q1.y));
    u32 w3 = cvt_pk_bf16(__uint_as_float(q1.z), __uint_as_float(q1.w));
    return __builtin_bit_cast(s16x8, make_uint4(w0, w1, w2, w3));
}

// Per-wave half-row scratch stride: 32 data words + 4 pad. 16 pairs per batch.
constexpr int SCW = 36;

// k4 identical to R6's proven 1.0x-write-amp version (do not change store shape).
__global__ __launch_bounds__(BLK, 4) void k4_mlp(
    const void* __restrict__ rf, const int* __restrict__ hdr,
    const int* __restrict__ perm, const uint4* __restrict__ wf,
    void* __restrict__ outp)
{
    __shared__ uint4 lw[L * NFRAG * 64];     // 28672 B: all weight frags
    __shared__ float sc[4][16 * SCW];        // 9216 B: per-wave 16-pair scratch
    __shared__ int   sn[4][2][32];           // 1024 B: per-wave pair indices
    __shared__ int   sf32;

    int tid = threadIdx.x;

    // bases from counts (padded prefix)
    int c0 = hdr[0], c1 = hdr[1], c2 = hdr[2], c3 = hdr[3];
    int b1 = (c0 + BLK - 1) & ~(BLK - 1);
    int b2 = b1 + ((c1 + BLK - 1) & ~(BLK - 1));
    int b3 = b2 + ((c2 + BLK - 1) & ~(BLK - 1));
    int b4 = b3 + ((c3 + BLK - 1) & ~(BLK - 1));
    int p0 = blockIdx.x * BLK;
    if (p0 >= b4) return;                    // uniform: whole block exits
    int s = (p0 >= b3) ? 3 : ((p0 >= b2) ? 2 : ((p0 >= b1) ? 1 : 0));
    s = __builtin_amdgcn_readfirstlane(s);

    if (tid < 64) {                          // inline fp32 detect (256B broadcast)
        u32 w  = ((const u32*)rf)[tid];
        u32 lo = w & 0xffffu;
        u32 ex = (lo >> 7) & 0xffu;
        int plausible = (lo == 0u || (ex >= 90u && ex <= 141u)) ? 1 : 0;
        u64 pm = __ballot(plausible);
        if (tid == 0) sf32 = (__popcll(pm) < 48) ? 1 : 0;
    }

    // stage all weight frags to LDS
#pragma unroll
    for (int c = 0; c < 7; c++) {
        int idx = tid + c * BLK;             // < 1792
        int l = idx / (NFRAG * 64);
        int r = idx - l * (NFRAG * 64);
        lw[idx] = wf[(size_t)((l * S + s) * NFRAG) * 64 + r];
    }

    int wv   = tid >> 6;
    int lane = tid & 63;
    int col  = lane & 31;
    int h    = lane >> 5;

    int n_t[2];
#pragma unroll
    for (int t = 0; t < 2; t++) {
        n_t[t] = perm[p0 + wv * 64 + t * 32 + col];
        sn[wv][t][col] = n_t[t];
    }
    __syncthreads();
    int isf32 = sf32;

    if (isf32) {
        // ---- fp32: j=(lp,t) loop, TWO independent l-chains interleaved (2x ILP),
        //      128B half-row stores via 16-pair LDS transpose batches ----
        const char* xb = (const char*)rf;
        int nn0 = n_t[0] < 0 ? 0 : n_t[0];
        int nn1 = n_t[1] < 0 ? 0 : n_t[1];
        const uint4* rp0 = (const uint4*)(xb + (size_t)nn0 * 256 + h * 32);
        const uint4* rp1 = (const uint4*)(xb + (size_t)nn1 * 256 + h * 32);

        int rg = lane >> 3;                  // 0..7: half-row group for stores
        int cc = lane & 7;                   // 0..7: 16B chunk within a 128B half-row
        int bh = col >> 4;                   // which 16-pair batch this lane's data is in
        int pr = col & 15;                   // pair index within batch
        float* scb = &sc[wv][0];

        // double-buffered input rows: rawb[buf][li*2 + half]
        uint4 rawb[2][4];
        rawb[0][0] = rp0[0]; rawb[0][1] = rp0[1];   // j=0: l=0
        rawb[0][2] = rp0[4]; rawb[0][3] = rp0[5];   //      l=1

#pragma unroll
        for (int j = 0; j < 4; j++) {               // j = lp*2 + t
            int lp = j >> 1, t = j & 1;
            if (j < 3) {                            // prefetch next (lp,t)
                int jn = j + 1;
                int lpn = jn >> 1, tn = jn & 1;
                const uint4* pl = tn ? rp1 : rp0;
                rawb[jn & 1][0] = pl[lpn * 8 + 0];
                rawb[jn & 1][1] = pl[lpn * 8 + 1];
                rawb[jn & 1][2] = pl[lpn * 8 + 4];
                rawb[jn & 1][3] = pl[lpn * 8 + 5];
            }
            int lA = 2 * lp, lB = 2 * lp + 1;
            s16x8 frA[NFRAG], frB[NFRAG];
#pragma unroll
            for (int f = 0; f < NFRAG; f++) {
                frA[f] = __builtin_bit_cast(s16x8, lw[(lA * NFRAG + f) * 64 + lane]);
                frB[f] = __builtin_bit_cast(s16x8, lw[(lB * NFRAG + f) * 64 + lane]);
            }

            s16x8 B1A = bf16pack4(rawb[j & 1][0], rawb[j & 1][1]);
            s16x8 B1B = bf16pack4(rawb[j & 1][2], rawb[j & 1][3]);

            f32x16 z = {0.0f};
            f32x16 dA = __builtin_amdgcn_mfma_f32_32x32x16_bf16(frA[0], B1A, z, 0, 0, 0);
            f32x16 dB = __builtin_amdgcn_mfma_f32_32x32x16_bf16(frB[0], B1B, z, 0, 0, 0);

            s16x8 BaA, BbA, BaB, BbB;
            d_to_b(dA, BaA, BbA);
            d_to_b(dB, BaB, BbB);
            dA = __builtin_amdgcn_mfma_f32_32x32x16_bf16(frA[1], BaA, z, 0, 0, 0);
            dB = __builtin_amdgcn_mfma_f32_32x32x16_bf16(frB[1], BaB, z, 0, 0, 0);
            dA = __builtin_amdgcn_mfma_f32_32x32x16_bf16(frA[2], BbA, dA, 0, 0, 0);
            dB = __builtin_amdgcn_mfma_f32_32x32x16_bf16(frB[2], BbB, dB, 0, 0, 0);

            d_to_b(dA, BaA, BbA);
            d_to_b(dB, BaB, BbB);
            dA = __builtin_amdgcn_mfma_f32_32x32x16_bf16(frA[3], BaA, z, 0, 0, 0);
            dB = __builtin_amdgcn_mfma_f32_32x32x16_bf16(frB[3], BaB, z, 0, 0, 0);
            dA = __builtin_amdgcn_mfma_f32_32x32x16_bf16(frA[4], BbA, dA, 0, 0, 0);
            dB = __builtin_amdgcn_mfma_f32_32x32x16_bf16(frB[4], BbB, dB, 0, 0, 0);

            d_to_b(dA, BaA, BbA);
            d_to_b(dB, BaB, BbB);
            dA = __builtin_amdgcn_mfma_f32_32x32x16_bf16(frA[5], BaA, z, 0, 0, 0);
            dB = __builtin_amdgcn_mfma_f32_32x32x16_bf16(frB[5], BaB, z, 0, 0, 0);
            dA = __builtin_amdgcn_mfma_f32_32x32x16_bf16(frA[6], BbA, dA, 0, 0, 0);
            dB = __builtin_amdgcn_mfma_f32_32x32x16_bf16(frB[6], BbB, dB, 0, 0, 0);

            // two 16-pair batches: stash -> lgkm sync -> full-128B-half-row stores
#pragma unroll
            for (int b = 0; b < 2; b++) {
                if (bh == b) {
                    // lane (col,h) owns feats 4h..4h+3 / 8+4h..11+4h of pair col;
                    // word = li*16 + feat (li: 0 = l even, 1 = l odd)
                    float* swA = scb + pr * SCW + 4 * h;
                    *(f32x4*)swA        = (f32x4){dA[0], dA[1], dA[2], dA[3]};
                    *(f32x4*)(swA + 8)  = (f32x4){dA[4], dA[5], dA[6], dA[7]};
                    float* swB = swA + 16;
                    *(f32x4*)swB        = (f32x4){dB[0], dB[1], dB[2], dB[3]};
                    *(f32x4*)(swB + 8)  = (f32x4){dB[4], dB[5], dB[6], dB[7]};
                }
                asm volatile("s_waitcnt lgkmcnt(0)" ::: "memory");
                __builtin_amdgcn_sched_barrier(0);

                // 2 store instrs; each: 8 lanes cover one FULL 128B half-row
#pragma unroll
                for (int i = 0; i < 2; i++) {
                    int lr = 8 * i + rg;               // 0..15 within batch
                    int r  = 16 * b + lr;
                    int n  = sn[wv][t][r];
                    const float* srd = scb + lr * SCW + 4 * cc;
                    f32x4 v = *(const f32x4*)srd;
                    if (n >= 0)
                        *(f32x4*)((char*)outp + (size_t)n * 256 + (size_t)lp * 128 + cc * 16) = v;
                }
                asm volatile("s_waitcnt lgkmcnt(0)" ::: "memory");
                __builtin_amdgcn_sched_barrier(0);
            }
        }
    } else {
        // ---------- bf16 path (permlane epilogue, frags from LDS) ----------
#pragma unroll
        for (int l = 0; l < L; l++) {
            s16x8 fr[NFRAG];
#pragma unroll
            for (int f = 0; f < NFRAG; f++)
                fr[f] = __builtin_bit_cast(s16x8, lw[(l * NFRAG + f) * 64 + lane]);

#pragma unroll
            for (int t = 0; t < 2; t++) {
                int n = n_t[t];
                int nn = n < 0 ? 0 : n;

                const char* xb = (const char*)rf;
                s16x8 B1 = __builtin_bit_cast(s16x8,
                     *(const uint4*)(xb + (size_t)nn * 128 + l * 32 + h * 16));

                f32x16 z = {0.0f};
                f32x16 d1 = __builtin_amdgcn_mfma_f32_32x32x16_bf16(fr[0], B1, z, 0, 0, 0);

                s16x8 Ba, Bb;
                d_to_b(d1, Ba, Bb);
                f32x16 d2 = __builtin_amdgcn_mfma_f32_32x32x16_bf16(fr[1], Ba, z, 0, 0, 0);
                d2 = __builtin_amdgcn_mfma_f32_32x32x16_bf16(fr[2], Bb, d2, 0, 0, 0);

                d_to_b(d2, Ba, Bb);
                f32x16 d3 = __builtin_amdgcn_mfma_f32_32x32x16_bf16(fr[3], Ba, z, 0, 0, 0);
                d3 = __builtin_amdgcn_mfma_f32_32x32x16_bf16(fr[4], Bb, d3, 0, 0, 0);

                d_to_b(d3, Ba, Bb);
                f32x16 d4 = __builtin_amdgcn_mfma_f32_32x32x16_bf16(fr[5], Ba, z, 0, 0, 0);
                d4 = __builtin_amdgcn_mfma_f32_32x32x16_bf16(fr[6], Bb, d4, 0, 0, 0);

                u32 P[4];
#pragma unroll
                for (int i = 0; i < 4; i++) P[i] = cvt_pk_bf16(d4[2 * i], d4[2 * i + 1]);
                u32x2 r02 = __builtin_amdgcn_permlane32_swap(P[0], P[2], false, false);
                u32x2 r13 = __builtin_amdgcn_permlane32_swap(P[1], P[3], false, false);
                if (n >= 0) {
                    uint4 v = make_uint4(r02[0], r13[0], r02[1], r13[1]);
                    char* ob = (char*)outp;
                    *(uint4*)(ob + (size_t)n * 128 + l * 32 + h * 16) = v;
                }
            }
        }
    }
}

extern "C" void kernel_launch(void* const* d_in, const int* in_sizes, int n_in,
                              void* d_out, int out_size, void* d_ws, size_t ws_size,
                              hipStream_t stream) {
    const void* rf     = d_in[0];
    const int* species = (const int*)d_in[1];
    const void* W1     = d_in[2];
    const void* W2     = d_in[3];
    const void* W3     = d_in[4];
    const void* W4     = d_in[5];

    int N = in_sizes[1];
    int* hdr   = (int*)d_ws;
    uint4* wf  = (uint4*)((char*)d_ws + 256);
    int* perm  = (int*)d_ws + WS_PERM_INT;

    int nb4   = (N + BLK * 4 - 1) / (BLK * 4);       // k1/k3 blocks (= NB)
    int nwp   = (WF_ENTRIES + BLK - 1) / BLK;
    int grid4 = (N + S * (BLK - 1) + BLK - 1) / BLK;

    // bbase scratch lives in the TAIL of d_out (S*nb4 ints, 4B-aligned since
    // out_size is a multiple of 256). Dead before k4, which overwrites all of
    // d_out. Keeps workspace footprint identical to the last known-good run.
    int* bbase = (int*)((char*)d_out + out_size) - (size_t)S * nb4;

    k_wprep   <<<dim3(nwp),  dim3(BLK), 0, stream>>>(W1, W2, W3, W4,
                                                     (const u32*)rf, hdr, wf);
    k1_hist   <<<dim3(nb4),  dim3(BLK), 0, stream>>>(species, bbase, N, nb4);
    k2_scan   <<<dim3(1),    dim3(BLK), 0, stream>>>(hdr, bbase, nb4);
    k3_scatter<<<dim3(nb4),  dim3(BLK), 0, stream>>>(species, hdr, bbase, perm, N, nb4);
    k4_mlp    <<<dim3(grid4),dim3(BLK), 0, stream>>>(rf, hdr, perm, wf, d_out);
}